// Round 9
// baseline (347.315 us; speedup 1.0000x reference)
//
#include <hip/hip_runtime.h>

#define TOKENS 4096
#define HDIM   1024
#define EDIM   8
#define CAP    1536
#define TAU    0.03f

typedef float f32x4 __attribute__((ext_vector_type(4)));
typedef short bf16x8 __attribute__((ext_vector_type(8)));

static __device__ __forceinline__ unsigned short f2bf(float f) {
    unsigned int u = __float_as_uint(f);
    return (unsigned short)((u + 0x7fffu + ((u >> 16) & 1u)) >> 16);  // RNE
}
static __device__ __forceinline__ unsigned pk(float a, float b) {
    return (unsigned)f2bf(a) | ((unsigned)f2bf(b) << 16);
}

// ---------------- prep: X->bf16, W1->W1T bf16, zero logits/flags, 268MB fill ----------------
// grid 1024x256 = 262144 threads. Barrier-free, streaming. [verified R6]
__global__ __launch_bounds__(256) void prep_k(
    const float* __restrict__ X, const float* __restrict__ W1,
    unsigned short* __restrict__ Xbf, unsigned short* __restrict__ W1T,
    float* __restrict__ logits, int* __restrict__ flagsnf,
    float* __restrict__ zfill)
{
    const int id = blockIdx.x * 256 + threadIdx.x;

    // X convert: 4096*1024 floats = 524,288 units of 8 floats -> 2 per thread
#pragma unroll
    for (int i = 0; i < 2; i++) {
        const size_t u = (size_t)i * 262144 + id;
        const float* p = X + u * 8;
        float4 a = *(const float4*)(p);
        float4 b = *(const float4*)(p + 4);
        uint4 w;
        w.x = pk(a.x, a.y); w.y = pk(a.z, a.w);
        w.z = pk(b.x, b.y); w.w = pk(b.z, b.w);
        ((uint4*)Xbf)[u] = w;
    }

    // W1 -> W1T (k-contiguous): 131072 threads, one 8-k group each
    if (id < 131072) {
        const int n = id & 1023, kg = id >> 10;   // kg 0..127
        float v[8];
#pragma unroll
        for (int j = 0; j < 8; j++) v[j] = W1[(size_t)(kg * 8 + j) * 1024 + n];
        uint4 w;
        w.x = pk(v[0], v[1]); w.y = pk(v[2], v[3]);
        w.z = pk(v[4], v[5]); w.w = pk(v[6], v[7]);
        ((uint4*)W1T)[(size_t)n * 128 + kg] = w;
    }

    // zero logits (32768 f32 = 8192 f32x4) and flags+nf
    const f32x4 z4 = {0.f, 0.f, 0.f, 0.f};
    if (id < 8192) ((f32x4*)logits)[id] = z4;
    if (id < 9) flagsnf[id] = 0;

    // 268 MB zero-fill: 64 NT stores/thread, fully coalesced (16,777,216 f32x4)
    f32x4* Z = (f32x4*)zfill + id;
#pragma unroll
    for (int i = 0; i < 64; i++)
        __builtin_nontemporal_store(z4, Z + (size_t)i * 262144);
}

// ---------------- fused GEMM: logits += relu(X@W1+b1) @ W2, + 134MB fill ----------------
// Barrier-free: MFMA fragments gathered directly from global bf16 (L1/L2-hot).
// A and B use the IDENTICAL lane->(row,k) map => any HW k-permutation cancels.
// [verified R6, absmax 0.0039] 512 blocks, 4 waves, wave tile 32x64.
__global__ __launch_bounds__(256) void gemm_fused(
    const unsigned short* __restrict__ Xbf, const unsigned short* __restrict__ W1T,
    const float* __restrict__ b1, const float* __restrict__ W2,
    float* __restrict__ logits, float* __restrict__ zfill2)
{
    const int tid = threadIdx.x;
    const int w = tid >> 6, lane = tid & 63;
    const int g = lane >> 4, r = lane & 15;
    const int m0 = blockIdx.y * 64, n0 = blockIdx.x * 128;
    const int wm = (w >> 1) * 32, wn = (w & 1) * 64;

    const unsigned short* Ap = Xbf + (size_t)(m0 + wm + r) * 1024 + g * 8;
    const unsigned short* Bp = W1T + (size_t)(n0 + wn + r) * 1024 + g * 8;

    const int blk = blockIdx.y * 8 + blockIdx.x;          // 0..511
    f32x4* Z = (f32x4*)zfill2 + (size_t)blk * 256 + tid;  // stride 131072 per store
    const f32x4 z4 = {0.f, 0.f, 0.f, 0.f};

    f32x4 acc[2][4] = {};
    for (int it = 0; it < 32; ++it) {
        const int ko = it * 32;
        bf16x8 af[2], bfr[4];
#pragma unroll
        for (int i = 0; i < 2; i++) af[i]  = *(const bf16x8*)(Ap + i * 16384 + ko);
#pragma unroll
        for (int j = 0; j < 4; j++) bfr[j] = *(const bf16x8*)(Bp + j * 16384 + ko);

        __builtin_nontemporal_store(z4, Z + (size_t)(it * 2 + 0) * 131072);
        __builtin_nontemporal_store(z4, Z + (size_t)(it * 2 + 1) * 131072);

#pragma unroll
        for (int i = 0; i < 2; i++)
#pragma unroll
            for (int j = 0; j < 4; j++)
                acc[i][j] = __builtin_amdgcn_mfma_f32_16x16x32_bf16(af[i], bfr[j], acc[i][j], 0, 0, 0);
    }

    // epilogue: h = relu(acc + b1[col]); plocal[row][e] += h * W2[col][e]
    float plocal[8][8];
#pragma unroll
    for (int a = 0; a < 8; a++)
#pragma unroll
        for (int e = 0; e < 8; e++) plocal[a][e] = 0.f;

#pragma unroll
    for (int j = 0; j < 4; j++) {
        const int col = n0 + wn + j * 16 + r;
        const float bias = b1[col];
        float4 w2a = *(const float4*)(W2 + (size_t)col * 8);
        float4 w2b = *(const float4*)(W2 + (size_t)col * 8 + 4);
        float w2v[8] = {w2a.x, w2a.y, w2a.z, w2a.w, w2b.x, w2b.y, w2b.z, w2b.w};
#pragma unroll
        for (int i = 0; i < 2; i++)
#pragma unroll
            for (int q = 0; q < 4; q++) {
                const float h = fmaxf(acc[i][j][q] + bias, 0.f);
#pragma unroll
                for (int e = 0; e < 8; e++)
                    plocal[i * 4 + q][e] = fmaf(h, w2v[e], plocal[i * 4 + q][e]);
            }
    }

#pragma unroll
    for (int off = 1; off < 16; off <<= 1)
#pragma unroll
        for (int a = 0; a < 8; a++)
#pragma unroll
            for (int e = 0; e < 8; e++)
                plocal[a][e] += __shfl_xor(plocal[a][e], off);

    if (r == 0) {
#pragma unroll
        for (int i = 0; i < 2; i++)
#pragma unroll
            for (int q = 0; q < 4; q++) {
                const int row = m0 + wm + i * 16 + g * 4 + q;
#pragma unroll
                for (int e = 0; e < 8; e++)
                    atomicAdd(&logits[(size_t)row * 8 + e], plocal[i * 4 + q][e]);
            }
    }
}

// ---------------- router2: softmax/top-3 from logits; flag risky tokens ----------------
__global__ __launch_bounds__(256) void router2_k(
    const float* __restrict__ logits, const float* __restrict__ b2,
    float* __restrict__ probs_out,
    int* __restrict__ e0a, int* __restrict__ e1a,
    float* __restrict__ p0a, float* __restrict__ p1a,
    int* __restrict__ flags, int* __restrict__ nf, int* __restrict__ list)
{
    const int t = blockIdx.x * 256 + threadIdx.x;
    if (t >= TOKENS) return;
    float4 la = *(const float4*)(logits + (size_t)t * 8);
    float4 lb = *(const float4*)(logits + (size_t)t * 8 + 4);
    float logit[8] = {la.x, la.y, la.z, la.w, lb.x, lb.y, lb.z, lb.w};
#pragma unroll
    for (int e = 0; e < 8; e++) logit[e] += b2[e];

    int e0 = 0; float m0 = logit[0];
#pragma unroll
    for (int e = 1; e < 8; e++) if (logit[e] > m0) { m0 = logit[e]; e0 = e; }
    int e1 = -1; float m1 = -1e30f;
#pragma unroll
    for (int e = 0; e < 8; e++) if (e != e0 && logit[e] > m1) { m1 = logit[e]; e1 = e; }
    float m2 = -1e30f;
#pragma unroll
    for (int e = 0; e < 8; e++) if (e != e0 && e != e1 && logit[e] > m2) m2 = logit[e];

    if ((m0 - m1 < TAU) || (m1 - m2 < TAU)) {
        int wdx = atomicAdd(nf, 1);
        list[wdx] = t;                       // exact fp32 recompute later
    } else {
        float p[8], s = 0.f;
#pragma unroll
        for (int e = 0; e < 8; e++) { p[e] = expf(logit[e] - m0); s += p[e]; }
        const float inv = 1.f / s;
#pragma unroll
        for (int e = 0; e < 8; e++) p[e] *= inv;
        float4 pa = {p[0], p[1], p[2], p[3]};
        float4 pb = {p[4], p[5], p[6], p[7]};
        *(float4*)(probs_out + (size_t)t * 8)     = pa;
        *(float4*)(probs_out + (size_t)t * 8 + 4) = pb;
        const float ps = p[e0] + p[e1];
        e0a[t] = e0;
        e1a[t] = e1;
        p0a[t] = p[e0] / ps;
        p1a[t] = p[e1] / ps;
        atomicOr(&flags[e0], 1);
    }
}

// ---------------- LDS-free exact fp32 recompute of h-rows for flagged tokens ----------------
// Block = 32 tokens x 64 cols. Thread = 8 tokens (wave-broadcast X reads) x 1 col
// (coalesced W1 reads). Pure register FMA chain, no barriers, no LDS.
__global__ __launch_bounds__(256) void rescue_v2(
    const float* __restrict__ X, const float* __restrict__ W1,
    const float* __restrict__ b1, float* __restrict__ Hout,
    const int* __restrict__ nf, const int* __restrict__ list)
{
    const int n  = nf[0];
    const int i0 = blockIdx.y * 32;
    if (i0 >= n) return;
    const int tid = threadIdx.x;
    const int col = blockIdx.x * 64 + (tid & 63);
    const int tg  = tid >> 6;                 // wave id: 8 tokens per wave

    int tok[8];
#pragma unroll
    for (int j = 0; j < 8; j++) {
        const int ii = i0 + tg * 8 + j;
        tok[j] = list[ii < n ? ii : n - 1];   // dup-clamp: same value written twice
    }

    float acc[8] = {0, 0, 0, 0, 0, 0, 0, 0};
    for (int k0 = 0; k0 < HDIM; k0 += 4) {
        float4 xv[8];
#pragma unroll
        for (int j = 0; j < 8; j++)
            xv[j] = *(const float4*)(X + (size_t)tok[j] * HDIM + k0);  // broadcast in wave
        const float w0 = W1[(size_t)(k0 + 0) * HDIM + col];            // coalesced
        const float w1 = W1[(size_t)(k0 + 1) * HDIM + col];
        const float w2 = W1[(size_t)(k0 + 2) * HDIM + col];
        const float w3 = W1[(size_t)(k0 + 3) * HDIM + col];
#pragma unroll
        for (int j = 0; j < 8; j++) {
            acc[j] = fmaf(xv[j].x, w0, acc[j]);
            acc[j] = fmaf(xv[j].y, w1, acc[j]);
            acc[j] = fmaf(xv[j].z, w2, acc[j]);
            acc[j] = fmaf(xv[j].w, w3, acc[j]);
        }
    }
    const float bias = b1[col];
#pragma unroll
    for (int j = 0; j < 8; j++)
        Hout[(size_t)tok[j] * HDIM + col] = fmaxf(acc[j] + bias, 0.f);
}

// ---------------- router over rescued tokens (exact fp32 h @ W2) ----------------
__global__ __launch_bounds__(256) void router_pass(
    const float* __restrict__ Hbuf, const float* __restrict__ W2,
    const float* __restrict__ b2, float* __restrict__ probs_out,
    int* __restrict__ e0a, int* __restrict__ e1a,
    float* __restrict__ p0a, float* __restrict__ p1a,
    int* __restrict__ flags, const int* __restrict__ nf, const int* __restrict__ list)
{
    const int wave = threadIdx.x >> 6;
    const int lane = threadIdx.x & 63;
    const int idx  = blockIdx.x * 4 + wave;
    if (idx >= nf[0]) return;
    const int token = list[idx];

    const float* hrow = Hbuf + (size_t)token * HDIM;
    float acc[8] = {0, 0, 0, 0, 0, 0, 0, 0};
#pragma unroll
    for (int k = 0; k < HDIM / 64; k++) {
        const int hidx = lane + (k << 6);
        const float hv = hrow[hidx];
        float4 wa = *(const float4*)(W2 + hidx * 8);
        float4 wb = *(const float4*)(W2 + hidx * 8 + 4);
        acc[0] = fmaf(hv, wa.x, acc[0]);
        acc[1] = fmaf(hv, wa.y, acc[1]);
        acc[2] = fmaf(hv, wa.z, acc[2]);
        acc[3] = fmaf(hv, wa.w, acc[3]);
        acc[4] = fmaf(hv, wb.x, acc[4]);
        acc[5] = fmaf(hv, wb.y, acc[5]);
        acc[6] = fmaf(hv, wb.z, acc[6]);
        acc[7] = fmaf(hv, wb.w, acc[7]);
    }
#pragma unroll
    for (int off = 32; off; off >>= 1)
#pragma unroll
        for (int e = 0; e < 8; e++) acc[e] += __shfl_xor(acc[e], off);

    if (lane == 0) {
        float logit[8];
#pragma unroll
        for (int e = 0; e < 8; e++) logit[e] = acc[e] + b2[e];
        int e0 = 0; float m0 = logit[0];
#pragma unroll
        for (int e = 1; e < 8; e++) if (logit[e] > m0) { m0 = logit[e]; e0 = e; }
        int e1 = -1; float m1 = -1e30f;
#pragma unroll
        for (int e = 0; e < 8; e++) if (e != e0 && logit[e] > m1) { m1 = logit[e]; e1 = e; }

        float p[8], s = 0.f;
#pragma unroll
        for (int e = 0; e < 8; e++) { p[e] = expf(logit[e] - m0); s += p[e]; }
        const float inv = 1.f / s;
#pragma unroll
        for (int e = 0; e < 8; e++) p[e] *= inv;
        float4 pa = {p[0], p[1], p[2], p[3]};
        float4 pb = {p[4], p[5], p[6], p[7]};
        *(float4*)(probs_out + (size_t)token * 8)     = pa;
        *(float4*)(probs_out + (size_t)token * 8 + 4) = pb;
        const float ps = p[e0] + p[e1];
        e0a[token] = e0;
        e1a[token] = e1;
        p0a[token] = p[e0] / ps;
        p1a[token] = p[e1] / ps;
        atomicOr(&flags[e0], 1);
    }
}

// ---------------- scatter dispatch/combine + aux loss (block 0) ----------------
__global__ __launch_bounds__(256) void scatter_aux_k(
    const int* __restrict__ e0a, const int* __restrict__ e1a,
    const float* __restrict__ p0a, const float* __restrict__ p1a,
    const int* __restrict__ flags,
    float* __restrict__ dispatch, float* __restrict__ combine,
    const float* __restrict__ probs, float* __restrict__ auxout)
{
    const int t = blockIdx.x * 256 + threadIdx.x;
    if (t < TOKENS) {
        const int e0 = e0a[t], e1 = e1a[t];
        const size_t b0 = ((size_t)t * EDIM + e0) * CAP;   // round-0 pick -> slot 0
        dispatch[b0] = 1.f;
        combine[b0]  = p0a[t];
        const int s1 = flags[e1] ? 1 : 0;                  // slot 1 iff e1 was anyone's round-0 pick
        const size_t b1 = ((size_t)t * EDIM + e1) * CAP + s1;
        dispatch[b1] = 1.f;
        combine[b1]  = p1a[t];
    }

    if (blockIdx.x == 0) {
        __shared__ float red[4][8];
        const int tid = threadIdx.x, lane = tid & 63, wave = tid >> 6;
        float acc[8] = {0, 0, 0, 0, 0, 0, 0, 0};
        for (int tt = tid; tt < TOKENS; tt += 256) {
            float4 a = *(const float4*)(probs + (size_t)tt * 8);
            float4 b = *(const float4*)(probs + (size_t)tt * 8 + 4);
            acc[0] += a.x; acc[1] += a.y; acc[2] += a.z; acc[3] += a.w;
            acc[4] += b.x; acc[5] += b.y; acc[6] += b.z; acc[7] += b.w;
        }
#pragma unroll
        for (int off = 32; off; off >>= 1)
#pragma unroll
            for (int e = 0; e < 8; e++) acc[e] += __shfl_xor(acc[e], off);
        if (lane == 0)
#pragma unroll
            for (int e = 0; e < 8; e++) red[wave][e] = acc[e];
        __syncthreads();
        if (tid == 0) {
            float aux = 0.f;
#pragma unroll
            for (int e = 0; e < 8; e++) {
                float pe = (red[0][e] + red[1][e] + red[2][e] + red[3][e]) * (1.f / TOKENS);
                aux += pe * logf(pe * (float)EDIM + 1e-9f);
            }
            *auxout = aux;
        }
    }
}

extern "C" void kernel_launch(void* const* d_in, const int* in_sizes, int n_in,
                              void* d_out, int out_size, void* d_ws, size_t ws_size,
                              hipStream_t stream)
{
    const float* X  = (const float*)d_in[0];
    const float* W1 = (const float*)d_in[1];
    const float* b1 = (const float*)d_in[2];
    const float* W2 = (const float*)d_in[3];
    const float* b2 = (const float*)d_in[4];

    float* out = (float*)d_out;
    const size_t dispN = (size_t)TOKENS * EDIM * CAP;   // 50,331,648 floats
    float* dispatch = out;
    float* combine  = out + dispN;
    float* probs    = out + 2 * dispN;
    float* auxout   = out + 2 * dispN + (size_t)TOKENS * EDIM;

    // fill split: prep zeroes first 268,435,456 B of [dispatch|combine], gemm the rest
    float* zfill1 = out;
    float* zfill2 = out + 268435456 / 4;

    // ws layout: hbuf [0,16MB) aliases Xbf [0,8MB) + W1T [8MB,10MB) (dead before rescue)
    char* base = (char*)d_ws;
    float*          hbuf = (float*)base;
    unsigned short* Xbf  = (unsigned short*)base;
    unsigned short* W1T  = (unsigned short*)(base + (8u << 20));
    float*          logits = (float*)(base + (16u << 20));
    char* pp = base + (16u << 20) + (TOKENS * EDIM * sizeof(float));
    int*   e0a  = (int*)pp;   pp += TOKENS * sizeof(int);
    int*   e1a  = (int*)pp;   pp += TOKENS * sizeof(int);
    float* p0a  = (float*)pp; pp += TOKENS * sizeof(float);
    float* p1a  = (float*)pp; pp += TOKENS * sizeof(float);
    int*   flags = (int*)pp;  pp += EDIM * sizeof(int);   // flags[8] + nf contiguous
    int*   nf    = (int*)pp;  pp += sizeof(int);
    int*   list  = (int*)pp;

    prep_k<<<1024, 256, 0, stream>>>(X, W1, Xbf, W1T, logits, flags, zfill1);
    gemm_fused<<<dim3(8, 64), 256, 0, stream>>>(Xbf, W1T, b1, W2, logits, zfill2);
    router2_k<<<16, 256, 0, stream>>>(logits, b2, probs, e0a, e1a, p0a, p1a, flags, nf, list);
    rescue_v2<<<dim3(16, 128), 256, 0, stream>>>(X, W1, b1, hbuf, nf, list);
    router_pass<<<1024, 256, 0, stream>>>(hbuf, W2, b2, probs, e0a, e1a, p0a, p1a, flags, nf, list);
    scatter_aux_k<<<16, 256, 0, stream>>>(e0a, e1a, p0a, p1a, flags, dispatch, combine, probs, auxout);
}

// Round 10
// 263.173 us; speedup vs baseline: 1.3197x; 1.3197x over previous
//
#include <hip/hip_runtime.h>

#define TOKENS 4096
#define HDIM   1024
#define EDIM   8
#define CAP    1536

typedef float f32x4 __attribute__((ext_vector_type(4)));

// ---------------- GEMM1 fp32 (8x8 thread tile) + fused 402MB NT zero-fill ----------------
// h = relu(X @ W1 + b1). Tile BM=128 x BN=64, BK=16, 128 threads (2 waves),
// 512 blocks = 2/CU. Thread tile 8x8 -> 1.0 LDS-bytes/FMA (balanced vs 128B/cyc LDS).
// B tile XOR-swizzled (f ^ (((f>>5)&1)<<2)) -> conflict-free b128 reads.
// A-reads are 8-lane broadcasts (conflict-free). Fill: 6 NT f32x4/thread/iter,
// issued after barrier1 so they drain under the ~2048-cycle FMA phase (R3-proven pattern).
#define BM 128
#define BN 64
#define BK 16

__global__ __launch_bounds__(128) void gemm_fill(
    const float* __restrict__ X, const float* __restrict__ W1,
    const float* __restrict__ b1, float* __restrict__ Hout,
    float* __restrict__ zfill, int* __restrict__ flags)
{
    __shared__ float As[BK][BM + 4];   // [k][m], stride 132 floats (528B, 16B-aligned)
    __shared__ float Bs[BK][BN + 4];   // [k][n swizzled], stride 68 floats (272B)
    const int tid = threadIdx.x;
    const int tx  = tid & 7;           // 8 col-groups of 8
    const int ty  = tid >> 3;          // 16 row-groups of 8
    const int m0  = blockIdx.y * BM, n0 = blockIdx.x * BN;

    // staging: A row = tid (one 64B line per lane); B kk = tid>>3, nb = (tid&7)*8
    const int bkk = tid >> 3;
    const int bnb = (tid & 7) * 8;
    const int bw1 = bnb ^ (((bnb >> 5) & 1) << 2);
    const int bw2 = (bnb + 4) ^ ((((bnb + 4) >> 5) & 1) << 2);
    const int f1  = (tx * 8) ^ ((((tx * 8) >> 5) & 1) << 2);
    const int f2  = (tx * 8 + 4) ^ ((((tx * 8 + 4) >> 5) & 1) << 2);

    const int blk = blockIdx.y * gridDim.x + blockIdx.x;   // 0..511
    if (blk == 0 && tid < 8) flags[tid] = 0;
    // fill: 402,653,184 B / 512 blocks = 49,152 f32x4 / 128 thr = 384 = 6 per iter
    f32x4* Z = (f32x4*)zfill + (size_t)blk * 49152 + tid;
    const f32x4 z4 = {0.f, 0.f, 0.f, 0.f};

    float acc[8][8] = {};
    for (int it = 0; it < 64; ++it) {
        const int k0 = it * BK;
        // ---- global loads
        const float* ap = X + (size_t)(m0 + tid) * HDIM + k0;
        float4 a0 = *(const float4*)(ap);
        float4 a1 = *(const float4*)(ap + 4);
        float4 a2 = *(const float4*)(ap + 8);
        float4 a3 = *(const float4*)(ap + 12);
        const float* bp = W1 + (size_t)(k0 + bkk) * HDIM + n0 + bnb;
        float4 b0 = *(const float4*)(bp);
        float4 b1v = *(const float4*)(bp + 4);

        // ---- LDS stage
        As[0][tid]  = a0.x; As[1][tid]  = a0.y; As[2][tid]  = a0.z; As[3][tid]  = a0.w;
        As[4][tid]  = a1.x; As[5][tid]  = a1.y; As[6][tid]  = a1.z; As[7][tid]  = a1.w;
        As[8][tid]  = a2.x; As[9][tid]  = a2.y; As[10][tid] = a2.z; As[11][tid] = a2.w;
        As[12][tid] = a3.x; As[13][tid] = a3.y; As[14][tid] = a3.z; As[15][tid] = a3.w;
        *(float4*)&Bs[bkk][bw1] = b0;
        *(float4*)&Bs[bkk][bw2] = b1v;
        __syncthreads();

        // ---- NT fill: drains under the FMA phase below
#pragma unroll
        for (int s = 0; s < 6; s++)
            __builtin_nontemporal_store(z4, Z + (size_t)(it * 6 + s) * 128);

        // ---- 8x8 register-tile FMA
#pragma unroll
        for (int kk = 0; kk < BK; kk++) {
            float4 av0 = *(const float4*)&As[kk][ty * 8];
            float4 av1 = *(const float4*)&As[kk][ty * 8 + 4];
            float4 bv0 = *(const float4*)&Bs[kk][f1];
            float4 bv1 = *(const float4*)&Bs[kk][f2];
            float a[8] = {av0.x, av0.y, av0.z, av0.w, av1.x, av1.y, av1.z, av1.w};
            float b[8] = {bv0.x, bv0.y, bv0.z, bv0.w, bv1.x, bv1.y, bv1.z, bv1.w};
#pragma unroll
            for (int i = 0; i < 8; i++)
#pragma unroll
                for (int j = 0; j < 8; j++)
                    acc[i][j] = fmaf(a[i], b[j], acc[i][j]);
        }
        __syncthreads();
    }

    // ---- epilogue: bias + relu + store
    float4 bias0 = *(const float4*)(b1 + n0 + tx * 8);
    float4 bias1 = *(const float4*)(b1 + n0 + tx * 8 + 4);
    float bb[8] = {bias0.x, bias0.y, bias0.z, bias0.w, bias1.x, bias1.y, bias1.z, bias1.w};
#pragma unroll
    for (int i = 0; i < 8; i++) {
        const int row = m0 + ty * 8 + i;
        float4 o0, o1;
        o0.x = fmaxf(acc[i][0] + bb[0], 0.f);
        o0.y = fmaxf(acc[i][1] + bb[1], 0.f);
        o0.z = fmaxf(acc[i][2] + bb[2], 0.f);
        o0.w = fmaxf(acc[i][3] + bb[3], 0.f);
        o1.x = fmaxf(acc[i][4] + bb[4], 0.f);
        o1.y = fmaxf(acc[i][5] + bb[5], 0.f);
        o1.z = fmaxf(acc[i][6] + bb[6], 0.f);
        o1.w = fmaxf(acc[i][7] + bb[7], 0.f);
        *(float4*)(Hout + (size_t)row * HDIM + n0 + tx * 8)     = o0;
        *(float4*)(Hout + (size_t)row * HDIM + n0 + tx * 8 + 4) = o1;
    }
}

// ---------------- Router: logits, softmax, top-2, flags (R3-proven) ----------------
__global__ __launch_bounds__(256) void router_k(
    const float* __restrict__ Hbuf, const float* __restrict__ W2,
    const float* __restrict__ b2, float* __restrict__ probs_out,
    int* __restrict__ e0a, int* __restrict__ e1a,
    float* __restrict__ p0a, float* __restrict__ p1a,
    int* __restrict__ flags)
{
    const int wave  = threadIdx.x >> 6;
    const int lane  = threadIdx.x & 63;
    const int token = (blockIdx.x << 2) + wave;

    const float* hrow = Hbuf + (size_t)token * HDIM;
    float acc[8] = {0, 0, 0, 0, 0, 0, 0, 0};
#pragma unroll
    for (int k = 0; k < HDIM / 64; k++) {
        const int hidx = lane + (k << 6);
        const float hv = hrow[hidx];
        float4 wa = *(const float4*)(W2 + hidx * 8);
        float4 wb = *(const float4*)(W2 + hidx * 8 + 4);
        acc[0] = fmaf(hv, wa.x, acc[0]);
        acc[1] = fmaf(hv, wa.y, acc[1]);
        acc[2] = fmaf(hv, wa.z, acc[2]);
        acc[3] = fmaf(hv, wa.w, acc[3]);
        acc[4] = fmaf(hv, wb.x, acc[4]);
        acc[5] = fmaf(hv, wb.y, acc[5]);
        acc[6] = fmaf(hv, wb.z, acc[6]);
        acc[7] = fmaf(hv, wb.w, acc[7]);
    }
#pragma unroll
    for (int off = 32; off; off >>= 1)
#pragma unroll
        for (int e = 0; e < 8; e++) acc[e] += __shfl_xor(acc[e], off);

    if (lane == 0) {
        float logit[8];
#pragma unroll
        for (int e = 0; e < 8; e++) logit[e] = acc[e] + b2[e];
        float mx = logit[0];
#pragma unroll
        for (int e = 1; e < 8; e++) mx = fmaxf(mx, logit[e]);
        float p[8], s = 0.f;
#pragma unroll
        for (int e = 0; e < 8; e++) { p[e] = expf(logit[e] - mx); s += p[e]; }
        const float inv = 1.f / s;
#pragma unroll
        for (int e = 0; e < 8; e++) p[e] *= inv;

        float4 pa = {p[0], p[1], p[2], p[3]};
        float4 pb = {p[4], p[5], p[6], p[7]};
        *(float4*)(probs_out + (size_t)token * 8)     = pa;
        *(float4*)(probs_out + (size_t)token * 8 + 4) = pb;

        int e0 = 0; float m0 = logit[0];
#pragma unroll
        for (int e = 1; e < 8; e++) if (logit[e] > m0) { m0 = logit[e]; e0 = e; }
        int e1 = -1; float m1 = -1e30f;
#pragma unroll
        for (int e = 0; e < 8; e++) if (e != e0 && logit[e] > m1) { m1 = logit[e]; e1 = e; }

        const float ps = p[e0] + p[e1];
        e0a[token] = e0;
        e1a[token] = e1;
        p0a[token] = p[e0] / ps;
        p1a[token] = p[e1] / ps;
        atomicOr(&flags[e0], 1);
    }
}

// ---------------- scatter dispatch/combine + aux loss (block 0) (R3-proven) ----------------
__global__ __launch_bounds__(256) void scatter_aux_k(
    const int* __restrict__ e0a, const int* __restrict__ e1a,
    const float* __restrict__ p0a, const float* __restrict__ p1a,
    const int* __restrict__ flags,
    float* __restrict__ dispatch, float* __restrict__ combine,
    const float* __restrict__ probs, float* __restrict__ auxout)
{
    const int t = blockIdx.x * 256 + threadIdx.x;
    if (t < TOKENS) {
        const int e0 = e0a[t], e1 = e1a[t];
        const size_t b0 = ((size_t)t * EDIM + e0) * CAP;   // round-0 pick -> slot 0
        dispatch[b0] = 1.f;
        combine[b0]  = p0a[t];
        const int s1 = flags[e1] ? 1 : 0;                  // slot 1 iff e1 was anyone's round-0 pick
        const size_t b1 = ((size_t)t * EDIM + e1) * CAP + s1;
        dispatch[b1] = 1.f;
        combine[b1]  = p1a[t];
    }

    if (blockIdx.x == 0) {
        __shared__ float red[4][8];
        const int tid = threadIdx.x, lane = tid & 63, wave = tid >> 6;
        float acc[8] = {0, 0, 0, 0, 0, 0, 0, 0};
        for (int tt = tid; tt < TOKENS; tt += 256) {
            float4 a = *(const float4*)(probs + (size_t)tt * 8);
            float4 b = *(const float4*)(probs + (size_t)tt * 8 + 4);
            acc[0] += a.x; acc[1] += a.y; acc[2] += a.z; acc[3] += a.w;
            acc[4] += b.x; acc[5] += b.y; acc[6] += b.z; acc[7] += b.w;
        }
#pragma unroll
        for (int off = 32; off; off >>= 1)
#pragma unroll
            for (int e = 0; e < 8; e++) acc[e] += __shfl_xor(acc[e], off);
        if (lane == 0)
#pragma unroll
            for (int e = 0; e < 8; e++) red[wave][e] = acc[e];
        __syncthreads();
        if (tid == 0) {
            float aux = 0.f;
#pragma unroll
            for (int e = 0; e < 8; e++) {
                float pe = (red[0][e] + red[1][e] + red[2][e] + red[3][e]) * (1.f / TOKENS);
                aux += pe * logf(pe * (float)EDIM + 1e-9f);
            }
            *auxout = aux;
        }
    }
}

extern "C" void kernel_launch(void* const* d_in, const int* in_sizes, int n_in,
                              void* d_out, int out_size, void* d_ws, size_t ws_size,
                              hipStream_t stream)
{
    const float* X  = (const float*)d_in[0];
    const float* W1 = (const float*)d_in[1];
    const float* b1 = (const float*)d_in[2];
    const float* W2 = (const float*)d_in[3];
    const float* b2 = (const float*)d_in[4];

    float* out = (float*)d_out;
    const size_t dispN = (size_t)TOKENS * EDIM * CAP;   // 50,331,648 floats
    float* dispatch = out;
    float* combine  = out + dispN;
    float* probs    = out + 2 * dispN;
    float* auxout   = out + 2 * dispN + (size_t)TOKENS * EDIM;

    // ws: hbuf fp32 h (16MB), then small arrays
    char* base = (char*)d_ws;
    float* hbuf = (float*)base;
    char* pp = base + (size_t)TOKENS * HDIM * sizeof(float);
    int*   e0a  = (int*)pp;   pp += TOKENS * sizeof(int);
    int*   e1a  = (int*)pp;   pp += TOKENS * sizeof(int);
    float* p0a  = (float*)pp; pp += TOKENS * sizeof(float);
    float* p1a  = (float*)pp; pp += TOKENS * sizeof(float);
    int*   flags = (int*)pp;

    // gemm zeroes ALL of dispatch+combine (402MB NT, hidden under FMAs) + flags
    gemm_fill<<<dim3(HDIM / BN, TOKENS / BM), 128, 0, stream>>>(
        X, W1, b1, hbuf, dispatch, flags);
    router_k<<<TOKENS / 4, 256, 0, stream>>>(hbuf, W2, b2, probs, e0a, e1a, p0a, p1a, flags);
    scatter_aux_k<<<TOKENS / 256, 256, 0, stream>>>(
        e0a, e1a, p0a, p1a, flags, dispatch, combine, probs, auxout);
}